// Round 3
// baseline (588.258 us; speedup 1.0000x reference)
//
#include <hip/hip_runtime.h>
#include <hip/hip_bf16.h>

// AttentionWithContext: out[b,f] = sum_t a[b,t] x[b,t,f],
//   a = exp(ait)/(sum_t exp(ait) + 1e-7),  ait = tanh(x@W + bias) . u
// R3: persistent blocks (1024), each owns 4 consecutive 64-t tiles of one b.
// Software pipeline: tile t+1's global loads stay in flight (registers)
// during tile t's MFMA/epilogue/numerator -> memory overlaps compute.
// x read from HBM exactly once (256 MiB). Numerator recomputed from the
// LDS bf16 tile; per-block cross-wave reduce -> 256 atomics/block.

#define BB 128
#define TT 2048
#define FF 256
#define TQ 64                 // timesteps per tile
#define TPB 4                 // tiles per block
#define NBLK (BB * (TT / (TQ * TPB)))   // 128 * 8 = 1024 blocks
#define LSTRIDE 264           // LDS row stride in bf16 elems (+8 pad)

using bf16x8 = __attribute__((ext_vector_type(8))) short;
using f32x4  = __attribute__((ext_vector_type(4))) float;
using u32x2  = __attribute__((ext_vector_type(2))) unsigned;

__device__ __forceinline__ unsigned short f2bf(float f) {
  union { float f; unsigned u; } v; v.f = f;
  unsigned r = v.u + 0x7fffu + ((v.u >> 16) & 1u);   // RNE
  return (unsigned short)(r >> 16);
}
__device__ __forceinline__ unsigned pk2bf(float a, float b) {
  __hip_bfloat162 h = __float22bfloat162_rn(make_float2(a, b));  // v_cvt_pk_bf16_f32
  union { __hip_bfloat162 h; unsigned u; } v; v.h = h;
  return v.u;
}

// ---------------- prep: Wt[g][k] = bf16(W[k][g]); zero num+denom ----------------
__global__ void prep(const float* __restrict__ W, unsigned short* __restrict__ Wt,
                     float* __restrict__ zr) {
  int i = blockIdx.x * 256 + threadIdx.x;
  if (i < FF * FF) {
    int f = i >> 8, g = i & 255;             // coalesced read of W[f][g]
    Wt[g * FF + f] = f2bf(W[i]);
  }
  int j = i - FF * FF;
  if (j >= 0 && j < BB * FF + BB) zr[j] = 0.f;
}

// ---------------- main fused kernel ----------------
__global__ __launch_bounds__(256, 4)
void attn_main(const float* __restrict__ x, const unsigned short* __restrict__ Wt,
               const float* __restrict__ bias, const float* __restrict__ uvec,
               float* __restrict__ num, float* __restrict__ denom) {
  __shared__ unsigned short xb[TQ * LSTRIDE];   // 33792 B (reused as nred at end)
  __shared__ float part[4][TQ];                 // per-wave g-partials of ait
  __shared__ float ebuf[TQ];                    // exp(ait)
  __shared__ float bu[512];                     // [0:256) bias, [256:512) -2*u

  const int tid  = threadIdx.x;
  const int wave = tid >> 6;
  const int lane = tid & 63;
  const int q    = lane >> 4;       // quad
  const int ln   = lane & 15;
  const int b    = blockIdx.x >> 3;            // batch row
  const int grp  = blockIdx.x & 7;             // tile group within row
  const long base = ((long)b * TT + (long)grp * (TPB * TQ)) * FF;
  const int gbase = wave * 64;

  if (tid < 256) { bu[tid] = bias[tid]; bu[256 + tid] = -2.f * uvec[tid]; }

  // su = sum of this thread's 16 u[g] (epilogue constant-term folding)
  float su = 0.f;
  #pragma unroll
  for (int gt = 0; gt < 4; ++gt)
    #pragma unroll
    for (int r = 0; r < 4; ++r)
      su += uvec[gbase + gt * 16 + q * 4 + r];

  // ---- prologue: issue loads for tile 0 ----
  const float* src = x + base + tid * 4;
  f32x4 v[16];
  #pragma unroll
  for (int r = 0; r < 16; ++r) v[r] = *(const f32x4*)(src + r * 1024);

  float na[4] = {0.f, 0.f, 0.f, 0.f};    // numerator accum: f = lane*4 .. +3
  float dacc  = 0.f;                     // denom accum (tid 0)

  for (int it = 0; it < TPB; ++it) {
    if (it) __syncthreads();        // all waves done reading xb/ebuf of prev tile

    // ---- convert in-flight regs -> LDS bf16 ----
    #pragma unroll
    for (int r = 0; r < 16; ++r) {
      int e = r * 1024 + tid * 4;
      int row = e >> 8, col = e & (FF - 1);
      u32x2 w = { pk2bf(v[r].x, v[r].y), pk2bf(v[r].z, v[r].w) };
      *(u32x2*)(&xb[row * LSTRIDE + col]) = w;
    }
    // ---- issue next tile's loads (in flight during this tile's compute) ----
    if (it < TPB - 1) {
      const float* nsrc = src + (long)(it + 1) * TQ * FF;
      #pragma unroll
      for (int r = 0; r < 16; ++r) v[r] = *(const f32x4*)(nsrc + r * 1024);
    }
    __syncthreads();

    // ---- MFMA: C[g][t_local]; wave owns g in [64*wave, 64*wave+64) ----
    f32x4 acc[4][TQ / 16];
    #pragma unroll
    for (int i = 0; i < 4; ++i)
      #pragma unroll
      for (int j = 0; j < TQ / 16; ++j)
        acc[i][j] = (f32x4){0.f, 0.f, 0.f, 0.f};

    #pragma unroll
    for (int kk = 0; kk < FF; kk += 32) {
      bf16x8 afr[4];
      #pragma unroll
      for (int gt = 0; gt < 4; ++gt) {
        int g = gbase + gt * 16 + ln;
        afr[gt] = *(const bf16x8*)(Wt + g * FF + kk + q * 8);  // A[m=ln][k], L2-hit
      }
      #pragma unroll
      for (int tt = 0; tt < TQ / 16; ++tt) {
        bf16x8 bfr = *(const bf16x8*)(&xb[(tt * 16 + ln) * LSTRIDE + kk + q * 8]);
        #pragma unroll
        for (int gt = 0; gt < 4; ++gt)
          acc[gt][tt] = __builtin_amdgcn_mfma_f32_16x16x32_bf16(afr[gt], bfr, acc[gt][tt], 0, 0, 0);
      }
    }

    // ---- epilogue: ait[t] = su + sum_g m2u[g]/(exp(2(C+bias))+1) ----
    #pragma unroll
    for (int tt = 0; tt < TQ / 16; ++tt) {
      float s = su;
      #pragma unroll
      for (int gt = 0; gt < 4; ++gt) {
        int g0 = gbase + gt * 16 + q * 4;
        f32x4 bi4 = *(const f32x4*)(&bu[g0]);
        f32x4 m24 = *(const f32x4*)(&bu[256 + g0]);
        #pragma unroll
        for (int r = 0; r < 4; ++r) {
          float vv = acc[gt][tt][r] + bi4[r];
          float e1 = __expf(2.f * vv) + 1.f;     // inf-safe
          s += m24[r] * __fdividef(1.f, e1);
        }
      }
      s += __shfl_xor(s, 16, 64);               // reduce across quads
      s += __shfl_xor(s, 32, 64);
      if (lane < 16) part[wave][tt * 16 + lane] = s;
    }
    __syncthreads();

    // ---- combine 4 waves, exp, denom partial (wave 0) ----
    if (tid < TQ) {
      float ait = part[0][tid] + part[1][tid] + part[2][tid] + part[3][tid];
      float e = __expf(ait);
      ebuf[tid] = e;
      float s2 = e;
      #pragma unroll
      for (int off = 32; off > 0; off >>= 1) s2 += __shfl_xor(s2, off, 64);
      if (tid == 0) dacc += s2;
    }
    __syncthreads();

    // ---- numerator partial from LDS: na[j] += sum_t e[t]*x[t][lane*4+j] ----
    {
      const int fp = lane * 4;
      const int t0 = wave * 16;
      #pragma unroll
      for (int i = 0; i < 16; ++i) {
        int tl = t0 + i;
        float e = ebuf[tl];
        u32x2 xv = *(const u32x2*)(&xb[tl * LSTRIDE + fp]);
        union { unsigned u; float f; } c0, c1, c2, c3;
        c0.u = xv.x << 16; c1.u = xv.x & 0xffff0000u;
        c2.u = xv.y << 16; c3.u = xv.y & 0xffff0000u;
        na[0] += e * c0.f; na[1] += e * c1.f;
        na[2] += e * c2.f; na[3] += e * c3.f;
      }
    }
  }

  // ---- cross-wave reduce numerator through LDS (xb reused), then atomics ----
  __syncthreads();                         // numerator reads of xb done
  float* nred = (float*)xb;                // 4 waves x 256 floats = 4 KB
  *(f32x4*)(&nred[wave * 256 + lane * 4]) = (f32x4){na[0], na[1], na[2], na[3]};
  __syncthreads();
  {
    float t0 = nred[tid] + nred[256 + tid] + nred[512 + tid] + nred[768 + tid];
    atomicAdd(&num[b * FF + tid], t0);
  }
  if (tid == 0) atomicAdd(&denom[b], dacc);
}

// ---------------- finalize: out = num / (denom + eps) ----------------
__global__ void finalize(const float* __restrict__ num, const float* __restrict__ denom,
                         float* __restrict__ out) {
  int i = blockIdx.x * 256 + threadIdx.x;    // 32768
  out[i] = num[i] / (denom[i >> 8] + 1e-7f);
}

extern "C" void kernel_launch(void* const* d_in, const int* in_sizes, int n_in,
                              void* d_out, int out_size, void* d_ws, size_t ws_size,
                              hipStream_t stream) {
  const float* x  = (const float*)d_in[0];
  const float* W  = (const float*)d_in[1];
  const float* bv = (const float*)d_in[2];
  const float* uv = (const float*)d_in[3];
  float* out = (float*)d_out;

  unsigned short* Wt = (unsigned short*)d_ws;                 // 131072 B
  float* num   = (float*)((char*)d_ws + FF * FF * 2);         // 131072 B
  float* denom = num + BB * FF;                               // 512 B

  prep<<<(FF * FF + BB * FF + BB + 255) / 256, 256, 0, stream>>>(W, Wt, num);
  attn_main<<<NBLK, 256, 0, stream>>>(x, Wt, bv, uv, num, denom);
  finalize<<<(BB * FF) / 256, 256, 0, stream>>>(num, denom, out);
}

// Round 4
// 385.980 us; speedup vs baseline: 1.5241x; 1.5241x over previous
//
#include <hip/hip_runtime.h>
#include <hip/hip_bf16.h>

// AttentionWithContext: out[b,f] = sum_t a[b,t] x[b,t,f],
//   a = exp(ait)/(sum_t exp(ait) + 1e-7),  ait = tanh(x@W + bias) . u
// R4: async-DMA pipeline. 512 blocks (2/CU), each owns 16 consecutive 32-t
// tiles of one b. x fp32 tiles staged to LDS via global_load_lds (width 16,
// zero VGPRs), double-buffered; raw s_barrier + manual s_waitcnt vmcnt(8)
// keeps next tile's DMAs in flight across the barrier (no __syncthreads in
// the loop -- it drains vmcnt(0) and would serialize the stream).
// Wt A-fragments preloaded to registers once (tile-invariant, 128 VGPRs,
// budget 256 at 2 waves/SIMD). fp32->bf16 cvt at B-fragment build.

#define BB 128
#define TT 2048
#define FF 256
#define TQ 32                  // timesteps per tile
#define NT 16                  // tiles per block
#define NBLK (BB * (TT / (TQ * NT)))   // 128 * 4 = 512 blocks = 2/CU
#define RS 260                 // LDS row stride in fp32 elems (256 + 4 pad = 1040 B)

// s_waitcnt imms: vmcnt[3:0]|[15:14], expcnt[6:4], lgkmcnt[11:8]
#define W_VM8   0x0F78         // vmcnt(8),  lgkm/exp no-wait
#define W_VM0   0x0F70         // vmcnt(0),  lgkm/exp no-wait
#define W_LGKM0 0xC07F         // lgkmcnt(0), vm/exp no-wait

using bf16x8 = __attribute__((ext_vector_type(8))) short;
using f32x4  = __attribute__((ext_vector_type(4))) float;

typedef __attribute__((address_space(1))) const void* as1cv;
typedef __attribute__((address_space(3))) void* as3v;

__device__ __forceinline__ unsigned short f2bf(float f) {
  union { float f; unsigned u; } v; v.f = f;
  unsigned r = v.u + 0x7fffu + ((v.u >> 16) & 1u);   // RNE
  return (unsigned short)(r >> 16);
}
__device__ __forceinline__ unsigned pk2bf(float a, float b) {
  __hip_bfloat162 h = __float22bfloat162_rn(make_float2(a, b));  // v_cvt_pk_bf16_f32
  union { __hip_bfloat162 h; unsigned u; } v; v.h = h;
  return v.u;
}

template <int IMM>
__device__ __forceinline__ void wait_barrier() {
  asm volatile("" ::: "memory");
  __builtin_amdgcn_s_waitcnt(IMM);
  __builtin_amdgcn_s_barrier();
  asm volatile("" ::: "memory");
}

// ---------------- prep: Wt[g][k] = bf16(W[k][g]); zero num+denom ----------------
__global__ void prep(const float* __restrict__ W, unsigned short* __restrict__ Wt,
                     float* __restrict__ zr) {
  int i = blockIdx.x * 256 + threadIdx.x;
  if (i < FF * FF) {
    int f = i >> 8, g = i & 255;             // coalesced read of W[f][g]
    Wt[g * FF + f] = f2bf(W[i]);
  }
  int j = i - FF * FF;
  if (j >= 0 && j < BB * FF + BB) zr[j] = 0.f;
}

// ---------------- main fused kernel ----------------
__global__ __launch_bounds__(256, 2)
void attn_main(const float* __restrict__ x, const unsigned short* __restrict__ Wt,
               const float* __restrict__ bias, const float* __restrict__ uvec,
               float* __restrict__ num, float* __restrict__ denom) {
  __shared__ float xb[2][TQ * RS];     // 2 x 33280 B fp32 staging
  __shared__ float part[4][TQ];        // per-wave g-partials of ait

  const int tid  = threadIdx.x;
  const int wave = tid >> 6;
  const int lane = tid & 63;
  const int q    = lane >> 4;          // quad
  const int ln   = lane & 15;
  const int b    = blockIdx.x >> 2;    // batch row
  const int seg  = blockIdx.x & 3;     // 512-t segment
  const float* xt = x + ((long)b * TT + (long)seg * (NT * TQ)) * FF;
  const int gbase = wave * 64;

  // ---- issue tile 0 staging DMAs first (8 rows/wave, 1 KB each) ----
  {
    const float* gp = xt + lane * 4;
    #pragma unroll
    for (int r = 0; r < 8; ++r) {
      int row = wave * 8 + r;
      __builtin_amdgcn_global_load_lds((as1cv)(const void*)(gp + row * FF),
                                       (as3v)(void*)(&xb[0][row * RS]), 16, 0, 0);
    }
  }

  // ---- preload ALL Wt A-fragments (tile-invariant): 32 x 16B = 128 VGPRs ----
  bf16x8 afr[8][4];
  #pragma unroll
  for (int kk = 0; kk < 8; ++kk)
    #pragma unroll
    for (int gt = 0; gt < 4; ++gt)
      afr[kk][gt] = *(const bf16x8*)(Wt + (gbase + gt * 16 + ln) * FF + kk * 32 + q * 8);

  // ---- per-lane epilogue constants ----
  float bi[4][4], m2u[4][4], su = 0.f;
  #pragma unroll
  for (int gt = 0; gt < 4; ++gt)
    #pragma unroll
    for (int r = 0; r < 4; ++r) {
      int g = gbase + gt * 16 + q * 4 + r;   // C row = q*4 + reg
      bi[gt][r] = bias[g];
      float u = uvec[g];
      m2u[gt][r] = -2.f * u;
      su += u;
    }

  f32x4 na = {0.f, 0.f, 0.f, 0.f};     // numerator accum, f = lane*4..+3
  float dacc = 0.f;                    // denom accum (lane 0 valid)

  for (int it = 0; it < NT; ++it) {
    const int cur = it & 1;
    float* buf = xb[cur];

    // ---- issue next tile's DMAs into the other buffer ----
    if (it + 1 < NT) {
      const float* gp = xt + (long)(it + 1) * TQ * FF + lane * 4;
      float* obuf = xb[cur ^ 1];
      #pragma unroll
      for (int r = 0; r < 8; ++r) {
        int row = wave * 8 + r;
        __builtin_amdgcn_global_load_lds((as1cv)(const void*)(gp + row * FF),
                                         (as3v)(void*)(&obuf[row * RS]), 16, 0, 0);
      }
      wait_barrier<W_VM8>();   // current tile's 8 DMAs done; next 8 stay in flight
    } else {
      wait_barrier<W_VM0>();
    }

    // ---- MFMA: C[g][t]; wave owns g in [64w,64w+64); fp32->bf16 at B-build ----
    f32x4 acc[4][2];
    #pragma unroll
    for (int i = 0; i < 4; ++i) { acc[i][0] = (f32x4){0,0,0,0}; acc[i][1] = (f32x4){0,0,0,0}; }

    #pragma unroll
    for (int kk = 0; kk < 8; ++kk) {
      #pragma unroll
      for (int tt = 0; tt < 2; ++tt) {
        const float* p = &buf[(tt * 16 + ln) * RS + kk * 32 + q * 8];
        f32x4 v0 = *(const f32x4*)p;
        f32x4 v1 = *(const f32x4*)(p + 4);
        union { bf16x8 v; unsigned u[4]; } bb;
        bb.u[0] = pk2bf(v0.x, v0.y); bb.u[1] = pk2bf(v0.z, v0.w);
        bb.u[2] = pk2bf(v1.x, v1.y); bb.u[3] = pk2bf(v1.z, v1.w);
        #pragma unroll
        for (int gt = 0; gt < 4; ++gt)
          acc[gt][tt] = __builtin_amdgcn_mfma_f32_16x16x32_bf16(afr[kk][gt], bb.v, acc[gt][tt], 0, 0, 0);
      }
    }

    // ---- epilogue: ait = su + sum_g m2u[g]/(exp(2(C+bias))+1) ----
    #pragma unroll
    for (int tt = 0; tt < 2; ++tt) {
      float s = su;
      #pragma unroll
      for (int gt = 0; gt < 4; ++gt)
        #pragma unroll
        for (int r = 0; r < 4; ++r) {
          float vv = acc[gt][tt][r] + bi[gt][r];
          float e1 = __expf(2.f * vv) + 1.f;   // inf-safe tanh fold
          s += m2u[gt][r] * __fdividef(1.f, e1);
        }
      s += __shfl_xor(s, 16, 64);              // reduce across quads
      s += __shfl_xor(s, 32, 64);
      if (lane < 16) part[wave][tt * 16 + lane] = s;
    }
    wait_barrier<W_LGKM0>();

    // ---- e for this wave's 8 t-rows (redundant per 8 lanes, broadcast reads) ----
    const int tl = wave * 8 + (lane & 7);
    float ait = part[0][tl] + part[1][tl] + part[2][tl] + part[3][tl];
    float e = __expf(ait);
    float dp = (lane < 8) ? e : 0.f;
    dp += __shfl_xor(dp, 1, 64); dp += __shfl_xor(dp, 2, 64); dp += __shfl_xor(dp, 4, 64);
    dacc += dp;                                // lane 0 holds tile's denom partial

    // ---- numerator from fp32 LDS: na += e[t] * x[t][lane*4..+3] ----
    #pragma unroll
    for (int i = 0; i < 8; ++i) {
      float ev = __shfl(e, i, 64);             // e for t = wave*8 + i
      f32x4 xv = *(const f32x4*)(&buf[(wave * 8 + i) * RS + lane * 4]);
      na += xv * ev;
    }
    wait_barrier<W_LGKM0>();   // all reads of buf done before next-next DMA overwrites
  }

  // ---- cross-wave reduce numerator through LDS, then atomics ----
  __syncthreads();
  float* nred = &xb[0][0];                     // 4 x 256 floats
  *(f32x4*)(&nred[wave * 256 + lane * 4]) = na;
  __syncthreads();
  {
    float v = nred[tid] + nred[256 + tid] + nred[512 + tid] + nred[768 + tid];
    atomicAdd(&num[b * FF + tid], v);
  }
  if (lane == 0) atomicAdd(&denom[b], dacc);
}

// ---------------- finalize: out = num / (denom + eps) ----------------
__global__ void finalize(const float* __restrict__ num, const float* __restrict__ denom,
                         float* __restrict__ out) {
  int i = blockIdx.x * 256 + threadIdx.x;      // 32768
  out[i] = num[i] / (denom[i >> 8] + 1e-7f);
}

extern "C" void kernel_launch(void* const* d_in, const int* in_sizes, int n_in,
                              void* d_out, int out_size, void* d_ws, size_t ws_size,
                              hipStream_t stream) {
  const float* x  = (const float*)d_in[0];
  const float* W  = (const float*)d_in[1];
  const float* bv = (const float*)d_in[2];
  const float* uv = (const float*)d_in[3];
  float* out = (float*)d_out;

  unsigned short* Wt = (unsigned short*)d_ws;                 // 131072 B
  float* num   = (float*)((char*)d_ws + FF * FF * 2);         // 131072 B
  float* denom = num + BB * FF;                               // 512 B

  prep<<<(FF * FF + BB * FF + BB + 255) / 256, 256, 0, stream>>>(W, Wt, num);
  attn_main<<<NBLK, 256, 0, stream>>>(x, Wt, bv, uv, num, denom);
  finalize<<<(BB * FF) / 256, 256, 0, stream>>>(num, denom, out);
}